// Round 5
// baseline (320.817 us; speedup 1.0000x reference)
//
#include <hip/hip_runtime.h>

typedef __bf16 bf16_t;
typedef __bf16 bf16x4 __attribute__((ext_vector_type(4)));
typedef __bf16 bf16x8 __attribute__((ext_vector_type(8)));
typedef float  f32x4  __attribute__((ext_vector_type(4)));

// B=4, S=1024, D=1024, H=16, HD=64
// MFMA 16x16x32 bf16 layouts (m89/m91):
//   A-frag: row = lane&15, k = (lane>>4)*8 + j
//   B-frag: col = lane&15, k = (lane>>4)*8 + j  (from B^T rows)
//   C/D:    col = lane&15, row = (lane>>4)*4 + reg

__device__ __forceinline__ void gload16(const bf16_t* g, bf16_t* l) {
  __builtin_amdgcn_global_load_lds((const __attribute__((address_space(1))) void*)g,
                                   (__attribute__((address_space(3))) void*)l, 16, 0, 0);
}

// ---------------- fp32 -> bf16 elementwise ----------------
__global__ __launch_bounds__(256) void k_cvt_bf16(const float* __restrict__ in,
                                                  bf16_t* __restrict__ out) {
  int i = (blockIdx.x * 256 + threadIdx.x) * 4;
  const float4 v = *reinterpret_cast<const float4*>(in + i);
  bf16x4 o = { (bf16_t)v.x, (bf16_t)v.y, (bf16_t)v.z, (bf16_t)v.w };
  *reinterpret_cast<bf16x4*>(out + i) = o;
}

// ---------------- batched transpose + cvt: WT[n][k] = W[k][n], 4x 1024x1024 ----------------
__global__ __launch_bounds__(256) void k_transpose_cvt4(
    const float* __restrict__ W0, const float* __restrict__ W1,
    const float* __restrict__ W2, const float* __restrict__ W3,
    bf16_t* __restrict__ T0, bf16_t* __restrict__ T1,
    bf16_t* __restrict__ T2, bf16_t* __restrict__ T3) {
  const float* W; bf16_t* WT;
  switch (blockIdx.y) {
    case 0: W = W0; WT = T0; break;
    case 1: W = W1; WT = T1; break;
    case 2: W = W2; WT = T2; break;
    default: W = W3; WT = T3; break;
  }
  __shared__ float t[32][33];
  int bx = blockIdx.x & 31, by = blockIdx.x >> 5;
  int lx = threadIdx.x & 31, ly = threadIdx.x >> 5;  // 32 x 8
#pragma unroll
  for (int i = 0; i < 32; i += 8)
    t[ly + i][lx] = W[(size_t)(by * 32 + ly + i) * 1024 + bx * 32 + lx];
  __syncthreads();
#pragma unroll
  for (int i = 0; i < 32; i += 8)
    WT[(size_t)(bx * 32 + ly + i) * 1024 + by * 32 + lx] = (bf16_t)t[lx][ly + i];
}

// ---------------- content bias + mask: cbm[b,h,s] = (x@Wb)[b,s,h] + mask[b,s] ----------------
__global__ __launch_bounds__(256) void k_cbias(const float* __restrict__ x,
                                               const float* __restrict__ Wb,
                                               const float* __restrict__ mask,
                                               float* __restrict__ cbm) {
  int row = blockIdx.x;  // b*1024 + s
  int t = threadIdx.x;
  int h = t & 15, part = t >> 4;  // 16 heads x 16 k-parts of 64
  const float* xr = x + (size_t)row * 1024 + part * 64;
  const float* wb = Wb + (size_t)part * 64 * 16 + h;
  float s = 0.f;
#pragma unroll 8
  for (int i = 0; i < 64; ++i) s += xr[i] * wb[i * 16];
  __shared__ float ps[16][17];
  ps[part][h] = s;
  __syncthreads();
  if (t < 16) {
    float v = 0.f;
#pragma unroll
    for (int p = 0; p < 16; ++p) v += ps[p][t];
    cbm[((size_t)(row >> 10) * 16 + t) * 1024 + (row & 1023)] = v + mask[row];
  }
}

// ---------------- 128x128-tile bf16 GEMM, K=1024 (fused QKV, N=3072) ----------------
// nb 0..7 -> Q (*mixing/8, [b,h,s,d]), nb 8..15 -> K ([b,h,s,d]), nb 16..23 -> V^T ([b,h,d,s])
__global__ __launch_bounds__(256) void k_gemm_qkv(const bf16_t* __restrict__ A,
                                                  const bf16_t* __restrict__ BT,
                                                  const float* __restrict__ aux,
                                                  bf16_t* __restrict__ o0,
                                                  bf16_t* __restrict__ o1,
                                                  bf16_t* __restrict__ o2) {
  constexpr int K = 1024;
  const int tid = threadIdx.x;
  const int w = tid >> 6, lane = tid & 63;
  const int r = lane & 15, g = lane >> 4;
  const int swz = (blockIdx.x & 7) * 96 + (blockIdx.x >> 3);  // XCD-contiguous
  const int nb = swz % 24;
  const int mb = swz / 24;

  __shared__ bf16_t As[128 * 32];
  __shared__ bf16_t Bs[128 * 32];

  f32x4 acc[4][4] = {};

  const bf16_t* Ag = A + (size_t)(mb * 128 + w * 32 + (lane >> 2)) * K + (lane & 3) * 8;
  const bf16_t* Bg = BT + (size_t)(nb * 128 + w * 32 + (lane >> 2)) * K + (lane & 3) * 8;
  bf16_t* Asw = As + (w * 32) * 32;
  bf16_t* Bsw = Bs + (w * 32) * 32;

  const int mrow0 = (w >> 1) * 64, ncol0 = (w & 1) * 64;

  for (int k0 = 0; k0 < K; k0 += 32) {
    gload16(Ag + k0, Asw);
    gload16(Ag + 16 * K + k0, Asw + 16 * 32);
    gload16(Bg + k0, Bsw);
    gload16(Bg + 16 * K + k0, Bsw + 16 * 32);
    asm volatile("s_waitcnt vmcnt(0)" ::: "memory");
    __syncthreads();

    bf16x8 av[4], bv[4];
#pragma unroll
    for (int mi = 0; mi < 4; ++mi)
      av[mi] = *reinterpret_cast<const bf16x8*>(As + (mrow0 + mi * 16 + r) * 32 + g * 8);
#pragma unroll
    for (int ni = 0; ni < 4; ++ni)
      bv[ni] = *reinterpret_cast<const bf16x8*>(Bs + (ncol0 + ni * 16 + r) * 32 + g * 8);
#pragma unroll
    for (int mi = 0; mi < 4; ++mi)
#pragma unroll
      for (int ni = 0; ni < 4; ++ni)
        acc[mi][ni] = __builtin_amdgcn_mfma_f32_16x16x32_bf16(av[mi], bv[ni], acc[mi][ni], 0, 0, 0);
    __syncthreads();
  }

  const int row0 = mb * 128 + mrow0;
  const int matk = nb >> 3;
  const int col0 = (nb & 7) * 128 + ncol0;
#pragma unroll
  for (int mi = 0; mi < 4; ++mi)
#pragma unroll
    for (int ni = 0; ni < 4; ++ni)
#pragma unroll
      for (int rr = 0; rr < 4; ++rr) {
        int row = row0 + mi * 16 + g * 4 + rr;
        int col = col0 + ni * 16 + r;
        int h = col >> 6, dd = col & 63;
        size_t bh_ = (size_t)(row >> 10) * 16 + h;
        float v = acc[mi][ni][rr];
        if (matk == 0) {
          v *= aux[col] * 0.125f;  // mixing[h,dd] flat == col; fold 1/sqrt(64)
          o0[(bh_ * 1024 + (row & 1023)) * 64 + dd] = (bf16_t)v;
        } else if (matk == 1) {
          o1[(bh_ * 1024 + (row & 1023)) * 64 + dd] = (bf16_t)v;
        } else {
          o2[(bh_ * 64 + dd) * 1024 + (row & 1023)] = (bf16_t)v;
        }
      }
}

// ---------------- 64x128-tile dense GEMM, K=1024: out = A@Wd^T + bd (fp32, NT) ----------------
__global__ __launch_bounds__(256) void k_gemm_dense(const bf16_t* __restrict__ A,
                                                    const bf16_t* __restrict__ BT,
                                                    const float* __restrict__ bd,
                                                    float* __restrict__ of) {
  constexpr int K = 1024;
  const int tid = threadIdx.x;
  const int w = tid >> 6, lane = tid & 63;
  const int r = lane & 15, g = lane >> 4;
  const int swz = (blockIdx.x & 7) * 64 + (blockIdx.x >> 3);  // XCD-contiguous
  const int nb = swz & 7;
  const int mb = swz >> 3;

  __shared__ bf16_t As[64 * 32];
  __shared__ bf16_t Bs[128 * 32];

  f32x4 acc[2][4] = {};

  const bf16_t* Ag = A + (size_t)(mb * 64 + w * 16 + (lane >> 2)) * K + (lane & 3) * 8;
  const bf16_t* Bg = BT + (size_t)(nb * 128 + w * 32 + (lane >> 2)) * K + (lane & 3) * 8;
  bf16_t* Asw = As + (w * 16) * 32;
  bf16_t* Bsw = Bs + (w * 32) * 32;

  const int wr = w >> 1, wc = w & 1;  // wave -> 32x64 sub-tile
  const int mrow0 = wr * 32, ncol0 = wc * 64;

  for (int k0 = 0; k0 < K; k0 += 32) {
    gload16(Ag + k0, Asw);
    gload16(Bg + k0, Bsw);
    gload16(Bg + 16 * K + k0, Bsw + 16 * 32);
    asm volatile("s_waitcnt vmcnt(0)" ::: "memory");
    __syncthreads();

    bf16x8 av[2], bv[4];
#pragma unroll
    for (int mi = 0; mi < 2; ++mi)
      av[mi] = *reinterpret_cast<const bf16x8*>(As + (mrow0 + mi * 16 + r) * 32 + g * 8);
#pragma unroll
    for (int ni = 0; ni < 4; ++ni)
      bv[ni] = *reinterpret_cast<const bf16x8*>(Bs + (ncol0 + ni * 16 + r) * 32 + g * 8);
#pragma unroll
    for (int mi = 0; mi < 2; ++mi)
#pragma unroll
      for (int ni = 0; ni < 4; ++ni)
        acc[mi][ni] = __builtin_amdgcn_mfma_f32_16x16x32_bf16(av[mi], bv[ni], acc[mi][ni], 0, 0, 0);
    __syncthreads();
  }

  const int row0 = mb * 64 + mrow0, col0 = nb * 128 + ncol0;
#pragma unroll
  for (int mi = 0; mi < 2; ++mi)
#pragma unroll
    for (int ni = 0; ni < 4; ++ni)
#pragma unroll
      for (int rr = 0; rr < 4; ++rr) {
        int row = row0 + mi * 16 + g * 4 + rr;
        int col = col0 + ni * 16 + r;
        __builtin_nontemporal_store(acc[mi][ni][rr] + bd[col], of + (size_t)row * 1024 + col);
      }
}

// ---------------- scores + softmax -> P fp32 (write-roofline kernel) ----------------
// block: (b,h, 32 q-rows), 8 waves of 64. Wave w owns keys [w*128, w*128+128).
// Swapped QK^T: mfma(A=K_frag, B=Q_frag) -> C[key_local][q]:
//   lane(r,g), tile t, subtile qh: S[key = w*128+t*16+g*4+rr][q = qbase+qh*16+r].
// P streamed out via per-wave LDS bounce -> full 128B-line fp32 NT stores.
__global__ __launch_bounds__(512, 4) void k_attn_scores(const bf16_t* __restrict__ Qm,
                                                        const bf16_t* __restrict__ Kw,
                                                        const float* __restrict__ cbm,
                                                        float* __restrict__ P) {
  const int tid = threadIdx.x;
  const int w = tid >> 6, lane = tid & 63;
  const int r = lane & 15, g = lane >> 4;
  const int swz = (blockIdx.x & 7) * 256 + (blockIdx.x >> 3);  // XCD-contiguous bh
  const int qt = swz & 31;   // 32 tiles of 32 q rows
  const int bh = swz >> 5;
  const int qbase = qt * 32;

  __shared__ float red[2][32][8];
  __shared__ float bounce[8][16][36];  // per-wave 16x32 f32 tile, stride 36 (16B-aligned)

  // Q B-frags: q = qbase + qh*16 + r
  const bf16_t* qb = Qm + ((size_t)bh * 1024 + qbase) * 64;
  bf16x8 bq[2][2];
#pragma unroll
  for (int qh = 0; qh < 2; ++qh) {
    bq[qh][0] = *reinterpret_cast<const bf16x8*>(qb + (qh * 16 + r) * 64 + g * 8);
    bq[qh][1] = *reinterpret_cast<const bf16x8*>(qb + (qh * 16 + r) * 64 + 32 + g * 8);
  }

  // QK^T: 8 key tiles per wave
  const bf16_t* kb = Kw + ((size_t)bh * 1024 + w * 128) * 64;
  f32x4 acc[8][2];
#pragma unroll
  for (int t = 0; t < 8; ++t) {
    bf16x8 a0 = *reinterpret_cast<const bf16x8*>(kb + (t * 16 + r) * 64 + g * 8);
    bf16x8 a1 = *reinterpret_cast<const bf16x8*>(kb + (t * 16 + r) * 64 + 32 + g * 8);
#pragma unroll
    for (int qh = 0; qh < 2; ++qh) {
      f32x4 c = {0.f, 0.f, 0.f, 0.f};
      c = __builtin_amdgcn_mfma_f32_16x16x32_bf16(a0, bq[qh][0], c, 0, 0, 0);
      c = __builtin_amdgcn_mfma_f32_16x16x32_bf16(a1, bq[qh][1], c, 0, 0, 0);
      acc[t][qh] = c;
    }
  }

  // bias + per-lane max (keys vary across g,t; q fixed = r per qh)
  const float* cv = cbm + (size_t)bh * 1024 + w * 128;
  float mx[2] = {-1e30f, -1e30f};
#pragma unroll
  for (int t = 0; t < 8; ++t) {
    f32x4 c = *reinterpret_cast<const f32x4*>(cv + t * 16 + g * 4);
#pragma unroll
    for (int qh = 0; qh < 2; ++qh) {
      acc[t][qh] += c;
#pragma unroll
      for (int rr = 0; rr < 4; ++rr) mx[qh] = fmaxf(mx[qh], acc[t][qh][rr]);
    }
  }
#pragma unroll
  for (int qh = 0; qh < 2; ++qh) {
    mx[qh] = fmaxf(mx[qh], __shfl_xor(mx[qh], 16));
    mx[qh] = fmaxf(mx[qh], __shfl_xor(mx[qh], 32));
  }
  if (lane < 16) { red[0][r][w] = mx[0]; red[0][16 + r][w] = mx[1]; }
  __syncthreads();
  float m[2], sum[2] = {0.f, 0.f};
#pragma unroll
  for (int qh = 0; qh < 2; ++qh) {
    float v = red[0][qh * 16 + r][0];
#pragma unroll
    for (int ww = 1; ww < 8; ++ww) v = fmaxf(v, red[0][qh * 16 + r][ww]);
    m[qh] = v;
  }
#pragma unroll
  for (int t = 0; t < 8; ++t)
#pragma unroll
    for (int qh = 0; qh < 2; ++qh)
#pragma unroll
      for (int rr = 0; rr < 4; ++rr) {
        float p = __expf(acc[t][qh][rr] - m[qh]);
        acc[t][qh][rr] = p;
        sum[qh] += p;
      }
#pragma unroll
  for (int qh = 0; qh < 2; ++qh) {
    sum[qh] += __shfl_xor(sum[qh], 16);
    sum[qh] += __shfl_xor(sum[qh], 32);
  }
  if (lane < 16) { red[1][r][w] = sum[0]; red[1][16 + r][w] = sum[1]; }
  __syncthreads();
  float l[2];
#pragma unroll
  for (int qh = 0; qh < 2; ++qh) {
    float v = red[1][qh * 16 + r][0];
#pragma unroll
    for (int ww = 1; ww < 8; ++ww) v += red[1][qh * 16 + r][ww];
    l[qh] = 1.f / v;
  }

  // normalized P -> bounce (per-wave, no barriers) -> coalesced fp32 NT stores
  float* pg = P + ((size_t)bh * 1024 + qbase) * 1024 + w * 128;
  const int brow = lane >> 2, bc8 = (lane & 3) * 8;
#pragma unroll
  for (int qh = 0; qh < 2; ++qh)
#pragma unroll
    for (int kbk = 0; kbk < 4; ++kbk) {
      *reinterpret_cast<f32x4*>(&bounce[w][r][g * 4])      = acc[kbk * 2][qh] * l[qh];
      *reinterpret_cast<f32x4*>(&bounce[w][r][16 + g * 4]) = acc[kbk * 2 + 1][qh] * l[qh];
      f32x4 lo = *reinterpret_cast<const f32x4*>(&bounce[w][brow][bc8]);
      f32x4 hi = *reinterpret_cast<const f32x4*>(&bounce[w][brow][bc8 + 4]);
      float* dst = pg + (size_t)(qh * 16 + brow) * 1024 + kbk * 32 + bc8;
      __builtin_nontemporal_store(lo, reinterpret_cast<f32x4*>(dst));
      __builtin_nontemporal_store(hi, reinterpret_cast<f32x4*>(dst + 4));
    }
}

// ---------------- PV: streaming GEMM, P fp32 read straight into A-frags ----------------
// block: (b,h, 128 q-rows), 4 waves; wave w owns q rows [w*32, +32). No LDS, no barriers.
__global__ __launch_bounds__(256) void k_pv(const float* __restrict__ P,
                                            const bf16_t* __restrict__ VT,
                                            bf16_t* __restrict__ aout) {
  const int tid = threadIdx.x;
  const int w = tid >> 6, lane = tid & 63;
  const int r = lane & 15, g = lane >> 4;
  const int swz = (blockIdx.x & 7) * 64 + (blockIdx.x >> 3);  // XCD-contiguous bh
  const int qt = swz & 7;
  const int bh = swz >> 3;
  const int b = bh >> 4, h = bh & 15;
  const int q0 = qt * 128 + w * 32;

  const float* pr = P + ((size_t)bh * 1024 + q0) * 1024;
  const bf16_t* vb = VT + (size_t)bh * 64 * 1024;

  f32x4 acc[2][4] = {};
#pragma unroll 4
  for (int k0 = 0; k0 < 1024; k0 += 32) {
    bf16x8 af[2];
#pragma unroll
    for (int mi = 0; mi < 2; ++mi) {
      f32x4 plo = *reinterpret_cast<const f32x4*>(pr + (size_t)(mi * 16 + r) * 1024 + k0 + g * 8);
      f32x4 phi = *reinterpret_cast<const f32x4*>(pr + (size_t)(mi * 16 + r) * 1024 + k0 + g * 8 + 4);
      bf16x8 a;
      a[0] = (bf16_t)plo[0]; a[1] = (bf16_t)plo[1]; a[2] = (bf16_t)plo[2]; a[3] = (bf16_t)plo[3];
      a[4] = (bf16_t)phi[0]; a[5] = (bf16_t)phi[1]; a[6] = (bf16_t)phi[2]; a[7] = (bf16_t)phi[3];
      af[mi] = a;
    }
#pragma unroll
    for (int ni = 0; ni < 4; ++ni) {
      bf16x8 bf = *reinterpret_cast<const bf16x8*>(vb + (size_t)(ni * 16 + r) * 1024 + k0 + g * 8);
#pragma unroll
      for (int mi = 0; mi < 2; ++mi)
        acc[mi][ni] = __builtin_amdgcn_mfma_f32_16x16x32_bf16(af[mi], bf, acc[mi][ni], 0, 0, 0);
    }
  }
#pragma unroll
  for (int mi = 0; mi < 2; ++mi)
#pragma unroll
    for (int ni = 0; ni < 4; ++ni)
#pragma unroll
      for (int rr = 0; rr < 4; ++rr)
        aout[((size_t)b * 1024 + q0 + mi * 16 + g * 4 + rr) * 1024 + h * 64 + ni * 16 + r] =
            (bf16_t)acc[mi][ni][rr];
}

extern "C" void kernel_launch(void* const* d_in, const int* in_sizes, int n_in,
                              void* d_out, int out_size, void* d_ws, size_t ws_size,
                              hipStream_t stream) {
  const float* x      = (const float*)d_in[0];
  const float* mask   = (const float*)d_in[1];
  const float* Wq     = (const float*)d_in[2];
  const float* Wk     = (const float*)d_in[3];
  const float* Wv     = (const float*)d_in[4];
  const float* Wb     = (const float*)d_in[5];
  const float* mixing = (const float*)d_in[6];
  const float* Wd     = (const float*)d_in[7];
  const float* bd     = (const float*)d_in[8];

  char* ws = (char*)d_ws;
  bf16_t* xb   = (bf16_t*)(ws + 0);         //  8,388,608
  bf16_t* WqT  = (bf16_t*)(ws + 8388608);   //  2,097,152  } contiguous: one
  bf16_t* WkT  = (bf16_t*)(ws + 10485760);  //  2,097,152  } N=3072 B^T for
  bf16_t* WvT  = (bf16_t*)(ws + 12582912);  //  2,097,152  } fused QKV GEMM
  bf16_t* WdT  = (bf16_t*)(ws + 14680064);  //  2,097,152
  bf16_t* Qm   = (bf16_t*)(ws + 16777216);  //  8,388,608  [b,h,s,d] * mixing/8
  bf16_t* Kw   = (bf16_t*)(ws + 25165824);  //  8,388,608  [b,h,s,d]
  bf16_t* VT   = (bf16_t*)(ws + 33554432);  //  8,388,608  [b,h,d,s]
  bf16_t* aout = (bf16_t*)(ws + 41943040);  //  8,388,608  [b,s,(h,hd)]
  float*  cbm  = (float*)(ws + 50331648);   //    262,144  [b,h,s] bias+mask
  if (ws_size < 50593792) return;

  float* outO = (float*)d_out;        // attn_output [4,1024,1024]
  float* outP = outO + 4194304;       // attn_weights [4,16,1024,1024]

  k_cvt_bf16<<<4096, 256, 0, stream>>>(x, xb);
  k_transpose_cvt4<<<dim3(1024, 4), 256, 0, stream>>>(Wq, Wk, Wv, Wd, WqT, WkT, WvT, WdT);
  k_cbias<<<4096, 256, 0, stream>>>(x, Wb, mask, cbm);
  k_gemm_qkv<<<768, 256, 0, stream>>>(xb, WqT, mixing, Qm, Kw, VT);
  k_attn_scores<<<2048, 512, 0, stream>>>(Qm, Kw, cbm, outP);
  k_pv<<<512, 256, 0, stream>>>(outP, VT, aout);
  k_gemm_dense<<<512, 256, 0, stream>>>(aout, WdT, bd, outO);
}

// Round 6
// 265.537 us; speedup vs baseline: 1.2082x; 1.2082x over previous
//
#include <hip/hip_runtime.h>

typedef __bf16 bf16_t;
typedef __bf16 bf16x4 __attribute__((ext_vector_type(4)));
typedef __bf16 bf16x8 __attribute__((ext_vector_type(8)));
typedef float  f32x4  __attribute__((ext_vector_type(4)));

// B=4, S=1024, D=1024, H=16, HD=64
// MFMA 16x16x32 bf16 layouts (m89/m91):
//   A-frag: row = lane&15, k = (lane>>4)*8 + j
//   B-frag: col = lane&15, k = (lane>>4)*8 + j  (from B^T rows)
//   C/D:    col = lane&15, row = (lane>>4)*4 + reg

__device__ __forceinline__ void gload16(const bf16_t* g, bf16_t* l) {
  __builtin_amdgcn_global_load_lds((const __attribute__((address_space(1))) void*)g,
                                   (__attribute__((address_space(3))) void*)l, 16, 0, 0);
}

// ---------------- fp32 -> bf16 elementwise ----------------
__global__ __launch_bounds__(256) void k_cvt_bf16(const float* __restrict__ in,
                                                  bf16_t* __restrict__ out) {
  int i = (blockIdx.x * 256 + threadIdx.x) * 4;
  const float4 v = *reinterpret_cast<const float4*>(in + i);
  bf16x4 o = { (bf16_t)v.x, (bf16_t)v.y, (bf16_t)v.z, (bf16_t)v.w };
  *reinterpret_cast<bf16x4*>(out + i) = o;
}

// ---------------- batched transpose + cvt: WT[n][k] = W[k][n], 4x 1024x1024 ----------------
__global__ __launch_bounds__(256) void k_transpose_cvt4(
    const float* __restrict__ W0, const float* __restrict__ W1,
    const float* __restrict__ W2, const float* __restrict__ W3,
    bf16_t* __restrict__ T0, bf16_t* __restrict__ T1,
    bf16_t* __restrict__ T2, bf16_t* __restrict__ T3) {
  const float* W; bf16_t* WT;
  switch (blockIdx.y) {
    case 0: W = W0; WT = T0; break;
    case 1: W = W1; WT = T1; break;
    case 2: W = W2; WT = T2; break;
    default: W = W3; WT = T3; break;
  }
  __shared__ float t[32][33];
  int bx = blockIdx.x & 31, by = blockIdx.x >> 5;
  int lx = threadIdx.x & 31, ly = threadIdx.x >> 5;  // 32 x 8
#pragma unroll
  for (int i = 0; i < 32; i += 8)
    t[ly + i][lx] = W[(size_t)(by * 32 + ly + i) * 1024 + bx * 32 + lx];
  __syncthreads();
#pragma unroll
  for (int i = 0; i < 32; i += 8)
    WT[(size_t)(bx * 32 + ly + i) * 1024 + by * 32 + lx] = (bf16_t)t[lx][ly + i];
}

// ---------------- content bias + mask: cbm[b,h,s] = (x@Wb)[b,s,h] + mask[b,s] ----------------
__global__ __launch_bounds__(256) void k_cbias(const float* __restrict__ x,
                                               const float* __restrict__ Wb,
                                               const float* __restrict__ mask,
                                               float* __restrict__ cbm) {
  int row = blockIdx.x;  // b*1024 + s
  int t = threadIdx.x;
  int h = t & 15, part = t >> 4;  // 16 heads x 16 k-parts of 64
  const float* xr = x + (size_t)row * 1024 + part * 64;
  const float* wb = Wb + (size_t)part * 64 * 16 + h;
  float s = 0.f;
#pragma unroll 8
  for (int i = 0; i < 64; ++i) s += xr[i] * wb[i * 16];
  __shared__ float ps[16][17];
  ps[part][h] = s;
  __syncthreads();
  if (t < 16) {
    float v = 0.f;
#pragma unroll
    for (int p = 0; p < 16; ++p) v += ps[p][t];
    cbm[((size_t)(row >> 10) * 16 + t) * 1024 + (row & 1023)] = v + mask[row];
  }
}

// ---------------- 128x128-tile bf16 GEMM, K=1024 (fused QKV, N=3072) ----------------
// nb 0..7 -> Q (*mixing/8, [b,h,s,d]), nb 8..15 -> K ([b,h,s,d]), nb 16..23 -> V^T ([b,h,d,s])
__global__ __launch_bounds__(256) void k_gemm_qkv(const bf16_t* __restrict__ A,
                                                  const bf16_t* __restrict__ BT,
                                                  const float* __restrict__ aux,
                                                  bf16_t* __restrict__ o0,
                                                  bf16_t* __restrict__ o1,
                                                  bf16_t* __restrict__ o2) {
  constexpr int K = 1024;
  const int tid = threadIdx.x;
  const int w = tid >> 6, lane = tid & 63;
  const int r = lane & 15, g = lane >> 4;
  const int swz = (blockIdx.x & 7) * 96 + (blockIdx.x >> 3);  // XCD-contiguous
  const int nb = swz % 24;
  const int mb = swz / 24;

  __shared__ bf16_t As[128 * 32];
  __shared__ bf16_t Bs[128 * 32];

  f32x4 acc[4][4] = {};

  const bf16_t* Ag = A + (size_t)(mb * 128 + w * 32 + (lane >> 2)) * K + (lane & 3) * 8;
  const bf16_t* Bg = BT + (size_t)(nb * 128 + w * 32 + (lane >> 2)) * K + (lane & 3) * 8;
  bf16_t* Asw = As + (w * 32) * 32;
  bf16_t* Bsw = Bs + (w * 32) * 32;

  const int mrow0 = (w >> 1) * 64, ncol0 = (w & 1) * 64;

  for (int k0 = 0; k0 < K; k0 += 32) {
    gload16(Ag + k0, Asw);
    gload16(Ag + 16 * K + k0, Asw + 16 * 32);
    gload16(Bg + k0, Bsw);
    gload16(Bg + 16 * K + k0, Bsw + 16 * 32);
    asm volatile("s_waitcnt vmcnt(0)" ::: "memory");
    __syncthreads();

    bf16x8 av[4], bv[4];
#pragma unroll
    for (int mi = 0; mi < 4; ++mi)
      av[mi] = *reinterpret_cast<const bf16x8*>(As + (mrow0 + mi * 16 + r) * 32 + g * 8);
#pragma unroll
    for (int ni = 0; ni < 4; ++ni)
      bv[ni] = *reinterpret_cast<const bf16x8*>(Bs + (ncol0 + ni * 16 + r) * 32 + g * 8);
#pragma unroll
    for (int mi = 0; mi < 4; ++mi)
#pragma unroll
      for (int ni = 0; ni < 4; ++ni)
        acc[mi][ni] = __builtin_amdgcn_mfma_f32_16x16x32_bf16(av[mi], bv[ni], acc[mi][ni], 0, 0, 0);
    __syncthreads();
  }

  const int row0 = mb * 128 + mrow0;
  const int matk = nb >> 3;
  const int col0 = (nb & 7) * 128 + ncol0;
#pragma unroll
  for (int mi = 0; mi < 4; ++mi)
#pragma unroll
    for (int ni = 0; ni < 4; ++ni)
#pragma unroll
      for (int rr = 0; rr < 4; ++rr) {
        int row = row0 + mi * 16 + g * 4 + rr;
        int col = col0 + ni * 16 + r;
        int h = col >> 6, dd = col & 63;
        size_t bh_ = (size_t)(row >> 10) * 16 + h;
        float v = acc[mi][ni][rr];
        if (matk == 0) {
          v *= aux[col] * 0.125f;  // mixing[h,dd] flat == col; fold 1/sqrt(64)
          o0[(bh_ * 1024 + (row & 1023)) * 64 + dd] = (bf16_t)v;
        } else if (matk == 1) {
          o1[(bh_ * 1024 + (row & 1023)) * 64 + dd] = (bf16_t)v;
        } else {
          o2[(bh_ * 64 + dd) * 1024 + (row & 1023)] = (bf16_t)v;
        }
      }
}

// ---------------- 64x128-tile dense GEMM, K=1024: out = A@Wd^T + bd (fp32, NT) ----------------
__global__ __launch_bounds__(256) void k_gemm_dense(const bf16_t* __restrict__ A,
                                                    const bf16_t* __restrict__ BT,
                                                    const float* __restrict__ bd,
                                                    float* __restrict__ of) {
  constexpr int K = 1024;
  const int tid = threadIdx.x;
  const int w = tid >> 6, lane = tid & 63;
  const int r = lane & 15, g = lane >> 4;
  const int swz = (blockIdx.x & 7) * 64 + (blockIdx.x >> 3);  // XCD-contiguous
  const int nb = swz & 7;
  const int mb = swz >> 3;

  __shared__ bf16_t As[64 * 32];
  __shared__ bf16_t Bs[128 * 32];

  f32x4 acc[2][4] = {};

  const bf16_t* Ag = A + (size_t)(mb * 64 + w * 16 + (lane >> 2)) * K + (lane & 3) * 8;
  const bf16_t* Bg = BT + (size_t)(nb * 128 + w * 32 + (lane >> 2)) * K + (lane & 3) * 8;
  bf16_t* Asw = As + (w * 16) * 32;
  bf16_t* Bsw = Bs + (w * 32) * 32;

  const int wr = w >> 1, wc = w & 1;  // wave -> 32x64 sub-tile
  const int mrow0 = wr * 32, ncol0 = wc * 64;

  for (int k0 = 0; k0 < K; k0 += 32) {
    gload16(Ag + k0, Asw);
    gload16(Bg + k0, Bsw);
    gload16(Bg + 16 * K + k0, Bsw + 16 * 32);
    asm volatile("s_waitcnt vmcnt(0)" ::: "memory");
    __syncthreads();

    bf16x8 av[2], bv[4];
#pragma unroll
    for (int mi = 0; mi < 2; ++mi)
      av[mi] = *reinterpret_cast<const bf16x8*>(As + (mrow0 + mi * 16 + r) * 32 + g * 8);
#pragma unroll
    for (int ni = 0; ni < 4; ++ni)
      bv[ni] = *reinterpret_cast<const bf16x8*>(Bs + (ncol0 + ni * 16 + r) * 32 + g * 8);
#pragma unroll
    for (int mi = 0; mi < 2; ++mi)
#pragma unroll
      for (int ni = 0; ni < 4; ++ni)
        acc[mi][ni] = __builtin_amdgcn_mfma_f32_16x16x32_bf16(av[mi], bv[ni], acc[mi][ni], 0, 0, 0);
    __syncthreads();
  }

  const int row0 = mb * 64 + mrow0, col0 = nb * 128 + ncol0;
#pragma unroll
  for (int mi = 0; mi < 2; ++mi)
#pragma unroll
    for (int ni = 0; ni < 4; ++ni)
#pragma unroll
      for (int rr = 0; rr < 4; ++rr) {
        int row = row0 + mi * 16 + g * 4 + rr;
        int col = col0 + ni * 16 + r;
        __builtin_nontemporal_store(acc[mi][ni][rr] + bd[col], of + (size_t)row * 1024 + col);
      }
}

// ---------------- fused attn: QK^T(swapped) + softmax -> Plds ; PV ; P store LAST ----------------
// block: one (b,h), 16 q rows; 4 waves. Phase 1: wave w owns keys [w*256, w*256+256).
// Swapped QK^T: mfma(A=K_frag, B=Q_frag) => C[key_local][q]; lane(r,g) holds
// keys t*16+g*4+{0..3} for q=r. cbm read straight from global (L2-hot).
// CRITICAL ORDERING: no __syncthreads() after any global store — the barrier's
// implied vmcnt(0) would serialize the 64KB/block NT store drain into the
// critical path (R4/R5 lesson). PV runs first; P fp32 store is the last thing
// the wave does, draining overlapped with other blocks' compute.
__global__ __launch_bounds__(256, 4) void k_attn_fused(const bf16_t* __restrict__ Qm,
                                                       const bf16_t* __restrict__ Kw,
                                                       const bf16_t* __restrict__ VT,
                                                       const float* __restrict__ cbm,
                                                       float* __restrict__ P,
                                                       bf16_t* __restrict__ aout) {
  const int tid = threadIdx.x;
  const int w = tid >> 6, lane = tid & 63;
  const int r = lane & 15, g = lane >> 4;
  const int swz = (blockIdx.x & 7) * 512 + (blockIdx.x >> 3);  // XCD-contiguous (b,h) groups
  const int qt = swz & 63;
  const int bh = swz >> 6;
  const int b = bh >> 4, h = bh & 15;
  const int q0 = qt * 16;

  constexpr int PSTR = 1032;  // row stride 2064B = 516 dwords (516%32=4 -> 2-way, free)
  __shared__ float red[2][16][4];
  __shared__ bf16_t Plds[16 * PSTR];  // 32.25 KB

  // Q frags (B-operand): lane reads Q[q0 + r][g*8 ..] (+32)
  const bf16_t* qb = Qm + ((size_t)bh * 1024 + q0) * 64;
  bf16x8 bq0 = *reinterpret_cast<const bf16x8*>(qb + r * 64 + g * 8);
  bf16x8 bq1 = *reinterpret_cast<const bf16x8*>(qb + r * 64 + 32 + g * 8);

  // phase 1: S^T tiles. A-frag from K rows (key = t*16 + r).
  const bf16_t* kb = Kw + ((size_t)bh * 1024 + w * 256) * 64;
  f32x4 acc[16];
#pragma unroll
  for (int t = 0; t < 16; ++t) {
    bf16x8 a0 = *reinterpret_cast<const bf16x8*>(kb + (t * 16 + r) * 64 + g * 8);
    bf16x8 a1 = *reinterpret_cast<const bf16x8*>(kb + (t * 16 + r) * 64 + 32 + g * 8);
    f32x4 c = {0.f, 0.f, 0.f, 0.f};
    c = __builtin_amdgcn_mfma_f32_16x16x32_bf16(a0, bq0, c, 0, 0, 0);
    c = __builtin_amdgcn_mfma_f32_16x16x32_bf16(a1, bq1, c, 0, 0, 0);
    acc[t] = c;
  }

  // add bias+mask (direct from global, keys = w*256 + t*16 + g*4 + rr), per-lane max
  const float* cv = cbm + (size_t)bh * 1024 + w * 256;
  float mx = -1e30f;
#pragma unroll
  for (int t = 0; t < 16; ++t) {
    f32x4 c = *reinterpret_cast<const f32x4*>(cv + t * 16 + g * 4);
    acc[t] += c;
#pragma unroll
    for (int rr = 0; rr < 4; ++rr) mx = fmaxf(mx, acc[t][rr]);
  }
  mx = fmaxf(mx, __shfl_xor(mx, 16));
  mx = fmaxf(mx, __shfl_xor(mx, 32));
  if (lane < 16) red[0][r][w] = mx;
  __syncthreads();
  float m = fmaxf(fmaxf(red[0][r][0], red[0][r][1]), fmaxf(red[0][r][2], red[0][r][3]));
  float sum = 0.f;
#pragma unroll
  for (int t = 0; t < 16; ++t)
#pragma unroll
    for (int rr = 0; rr < 4; ++rr) {
      float p = __expf(acc[t][rr] - m);
      acc[t][rr] = p;
      sum += p;
    }
  sum += __shfl_xor(sum, 16);
  sum += __shfl_xor(sum, 32);
  if (lane < 16) red[1][r][w] = sum;
  __syncthreads();
  const float l = 1.f / (red[1][r][0] + red[1][r][1] + red[1][r][2] + red[1][r][3]);

  // normalized P -> LDS (bf16, rows = q)
  bf16_t* pl = Plds + r * PSTR + w * 256;
#pragma unroll
  for (int t = 0; t < 16; ++t) {
    f32x4 pv = acc[t] * l;
    bf16x4 pk = { (bf16_t)pv[0], (bf16_t)pv[1], (bf16_t)pv[2], (bf16_t)pv[3] };
    *reinterpret_cast<bf16x4*>(pl + t * 16 + g * 4) = pk;
  }
  __syncthreads();  // LDS-only waits: no global stores issued yet

  // phase 2: PV. wave w -> d-cols [w*16, w*16+16). A from Plds (q=r rows), B from VT rows.
  const bf16_t* vb = VT + ((size_t)bh * 64 + w * 16) * 1024;
  f32x4 oacc = {0.f, 0.f, 0.f, 0.f};
#pragma unroll 8
  for (int kbl = 0; kbl < 32; ++kbl) {
    bf16x8 av = *reinterpret_cast<const bf16x8*>(Plds + r * PSTR + kbl * 32 + g * 8);
    bf16x8 bv = *reinterpret_cast<const bf16x8*>(vb + (size_t)r * 1024 + kbl * 32 + g * 8);
    oacc = __builtin_amdgcn_mfma_f32_16x16x32_bf16(av, bv, oacc, 0, 0, 0);
  }
#pragma unroll
  for (int rr = 0; rr < 4; ++rr)
    aout[((size_t)b * 1024 + q0 + g * 4 + rr) * 1024 + h * 64 + w * 16 + r] = (bf16_t)oacc[rr];

  // phase 3 (LAST): P fp32 coalesced NT store from Plds. Wave w owns rows [w*4, w*4+4).
  // Drain overlaps other blocks' compute; nothing waits on it but s_endpgm.
  {
    float* pg = P + ((size_t)bh * 1024 + q0) * 1024;
#pragma unroll
    for (int j = 0; j < 4; ++j) {
      const int row = w * 4 + j;
#pragma unroll
      for (int half = 0; half < 2; ++half) {
        const int col = half * 512 + lane * 8;
        bf16x8 v = *reinterpret_cast<const bf16x8*>(Plds + row * PSTR + col);
        f32x4 lo = { (float)v[0], (float)v[1], (float)v[2], (float)v[3] };
        f32x4 hi = { (float)v[4], (float)v[5], (float)v[6], (float)v[7] };
        float* dst = pg + (size_t)row * 1024 + col;
        __builtin_nontemporal_store(lo, reinterpret_cast<f32x4*>(dst));
        __builtin_nontemporal_store(hi, reinterpret_cast<f32x4*>(dst + 4));
      }
    }
  }
}

extern "C" void kernel_launch(void* const* d_in, const int* in_sizes, int n_in,
                              void* d_out, int out_size, void* d_ws, size_t ws_size,
                              hipStream_t stream) {
  const float* x      = (const float*)d_in[0];
  const float* mask   = (const float*)d_in[1];
  const float* Wq     = (const float*)d_in[2];
  const float* Wk     = (const float*)d_in[3];
  const float* Wv     = (const float*)d_in[4];
  const float* Wb     = (const float*)d_in[5];
  const float* mixing = (const float*)d_in[6];
  const float* Wd     = (const float*)d_in[7];
  const float* bd     = (const float*)d_in[8];

  char* ws = (char*)d_ws;
  bf16_t* xb   = (bf16_t*)(ws + 0);         //  8,388,608
  bf16_t* WqT  = (bf16_t*)(ws + 8388608);   //  2,097,152  } contiguous: one
  bf16_t* WkT  = (bf16_t*)(ws + 10485760);  //  2,097,152  } N=3072 B^T for
  bf16_t* WvT  = (bf16_t*)(ws + 12582912);  //  2,097,152  } fused QKV GEMM
  bf16_t* WdT  = (bf16_t*)(ws + 14680064);  //  2,097,152
  bf16_t* Qm   = (bf16_t*)(ws + 16777216);  //  8,388,608  [b,h,s,d] * mixing/8
  bf16_t* Kw   = (bf16_t*)(ws + 25165824);  //  8,388,608  [b,h,s,d]
  bf16_t* VT   = (bf16_t*)(ws + 33554432);  //  8,388,608  [b,h,d,s]
  bf16_t* aout = (bf16_t*)(ws + 41943040);  //  8,388,608  [b,s,(h,hd)]
  float*  cbm  = (float*)(ws + 50331648);   //    262,144  [b,h,s] bias+mask
  if (ws_size < 50593792) return;

  float* outO = (float*)d_out;        // attn_output [4,1024,1024]
  float* outP = outO + 4194304;       // attn_weights [4,16,1024,1024]

  k_cvt_bf16<<<4096, 256, 0, stream>>>(x, xb);
  k_transpose_cvt4<<<dim3(1024, 4), 256, 0, stream>>>(Wq, Wk, Wv, Wd, WqT, WkT, WvT, WdT);
  k_cbias<<<4096, 256, 0, stream>>>(x, Wb, mask, cbm);
  k_gemm_qkv<<<768, 256, 0, stream>>>(xb, WqT, mixing, Qm, Kw, VT);
  k_attn_fused<<<4096, 256, 0, stream>>>(Qm, Kw, VT, cbm, outP, aout);
  k_gemm_dense<<<512, 256, 0, stream>>>(aout, WdT, bd, outO);
}

// Round 7
// 248.908 us; speedup vs baseline: 1.2889x; 1.0668x over previous
//
#include <hip/hip_runtime.h>

typedef __bf16 bf16_t;
typedef __bf16 bf16x4 __attribute__((ext_vector_type(4)));
typedef __bf16 bf16x8 __attribute__((ext_vector_type(8)));
typedef float  f32x4  __attribute__((ext_vector_type(4)));

// B=4, S=1024, D=1024, H=16, HD=64
// MFMA 16x16x32 bf16 layouts (m89/m91):
//   A-frag: row = lane&15, k = (lane>>4)*8 + j
//   B-frag: col = lane&15, k = (lane>>4)*8 + j  (from B^T rows)
//   C/D:    col = lane&15, row = (lane>>4)*4 + reg

__device__ __forceinline__ void gload16(const bf16_t* g, bf16_t* l) {
  __builtin_amdgcn_global_load_lds((const __attribute__((address_space(1))) void*)g,
                                   (__attribute__((address_space(3))) void*)l, 16, 0, 0);
}

// ---------------- fp32 -> bf16 elementwise ----------------
__global__ __launch_bounds__(256) void k_cvt_bf16(const float* __restrict__ in,
                                                  bf16_t* __restrict__ out) {
  int i = (blockIdx.x * 256 + threadIdx.x) * 4;
  const float4 v = *reinterpret_cast<const float4*>(in + i);
  bf16x4 o = { (bf16_t)v.x, (bf16_t)v.y, (bf16_t)v.z, (bf16_t)v.w };
  *reinterpret_cast<bf16x4*>(out + i) = o;
}

// ---------------- batched transpose + cvt: WT[n][k] = W[k][n], 4x 1024x1024 ----------------
__global__ __launch_bounds__(256) void k_transpose_cvt4(
    const float* __restrict__ W0, const float* __restrict__ W1,
    const float* __restrict__ W2, const float* __restrict__ W3,
    bf16_t* __restrict__ T0, bf16_t* __restrict__ T1,
    bf16_t* __restrict__ T2, bf16_t* __restrict__ T3) {
  const float* W; bf16_t* WT;
  switch (blockIdx.y) {
    case 0: W = W0; WT = T0; break;
    case 1: W = W1; WT = T1; break;
    case 2: W = W2; WT = T2; break;
    default: W = W3; WT = T3; break;
  }
  __shared__ float t[32][33];
  int bx = blockIdx.x & 31, by = blockIdx.x >> 5;
  int lx = threadIdx.x & 31, ly = threadIdx.x >> 5;  // 32 x 8
#pragma unroll
  for (int i = 0; i < 32; i += 8)
    t[ly + i][lx] = W[(size_t)(by * 32 + ly + i) * 1024 + bx * 32 + lx];
  __syncthreads();
#pragma unroll
  for (int i = 0; i < 32; i += 8)
    WT[(size_t)(bx * 32 + ly + i) * 1024 + by * 32 + lx] = (bf16_t)t[lx][ly + i];
}

// ---------------- content bias + mask: cbm[b,h,s] = (x@Wb)[b,s,h] + mask[b,s] ----------------
__global__ __launch_bounds__(256) void k_cbias(const float* __restrict__ x,
                                               const float* __restrict__ Wb,
                                               const float* __restrict__ mask,
                                               float* __restrict__ cbm) {
  int row = blockIdx.x;  // b*1024 + s
  int t = threadIdx.x;
  int h = t & 15, part = t >> 4;  // 16 heads x 16 k-parts of 64
  const float* xr = x + (size_t)row * 1024 + part * 64;
  const float* wb = Wb + (size_t)part * 64 * 16 + h;
  float s = 0.f;
#pragma unroll 8
  for (int i = 0; i < 64; ++i) s += xr[i] * wb[i * 16];
  __shared__ float ps[16][17];
  ps[part][h] = s;
  __syncthreads();
  if (t < 16) {
    float v = 0.f;
#pragma unroll
    for (int p = 0; p < 16; ++p) v += ps[p][t];
    cbm[((size_t)(row >> 10) * 16 + t) * 1024 + (row & 1023)] = v + mask[row];
  }
}

// ---------------- 128x128-tile bf16 GEMM, K=1024 (fused QKV, N=3072) ----------------
// nb 0..7 -> Q (*mixing/8, [b,h,s,d]), nb 8..15 -> K ([b,h,s,d]), nb 16..23 -> V^T ([b,h,d,s])
__global__ __launch_bounds__(256) void k_gemm_qkv(const bf16_t* __restrict__ A,
                                                  const bf16_t* __restrict__ BT,
                                                  const float* __restrict__ aux,
                                                  bf16_t* __restrict__ o0,
                                                  bf16_t* __restrict__ o1,
                                                  bf16_t* __restrict__ o2) {
  constexpr int K = 1024;
  const int tid = threadIdx.x;
  const int w = tid >> 6, lane = tid & 63;
  const int r = lane & 15, g = lane >> 4;
  const int swz = (blockIdx.x & 7) * 96 + (blockIdx.x >> 3);  // XCD-contiguous
  const int nb = swz % 24;
  const int mb = swz / 24;

  __shared__ bf16_t As[128 * 32];
  __shared__ bf16_t Bs[128 * 32];

  f32x4 acc[4][4] = {};

  const bf16_t* Ag = A + (size_t)(mb * 128 + w * 32 + (lane >> 2)) * K + (lane & 3) * 8;
  const bf16_t* Bg = BT + (size_t)(nb * 128 + w * 32 + (lane >> 2)) * K + (lane & 3) * 8;
  bf16_t* Asw = As + (w * 32) * 32;
  bf16_t* Bsw = Bs + (w * 32) * 32;

  const int mrow0 = (w >> 1) * 64, ncol0 = (w & 1) * 64;

  for (int k0 = 0; k0 < K; k0 += 32) {
    gload16(Ag + k0, Asw);
    gload16(Ag + 16 * K + k0, Asw + 16 * 32);
    gload16(Bg + k0, Bsw);
    gload16(Bg + 16 * K + k0, Bsw + 16 * 32);
    asm volatile("s_waitcnt vmcnt(0)" ::: "memory");
    __syncthreads();

    bf16x8 av[4], bv[4];
#pragma unroll
    for (int mi = 0; mi < 4; ++mi)
      av[mi] = *reinterpret_cast<const bf16x8*>(As + (mrow0 + mi * 16 + r) * 32 + g * 8);
#pragma unroll
    for (int ni = 0; ni < 4; ++ni)
      bv[ni] = *reinterpret_cast<const bf16x8*>(Bs + (ncol0 + ni * 16 + r) * 32 + g * 8);
#pragma unroll
    for (int mi = 0; mi < 4; ++mi)
#pragma unroll
      for (int ni = 0; ni < 4; ++ni)
        acc[mi][ni] = __builtin_amdgcn_mfma_f32_16x16x32_bf16(av[mi], bv[ni], acc[mi][ni], 0, 0, 0);
    __syncthreads();
  }

  const int row0 = mb * 128 + mrow0;
  const int matk = nb >> 3;
  const int col0 = (nb & 7) * 128 + ncol0;
#pragma unroll
  for (int mi = 0; mi < 4; ++mi)
#pragma unroll
    for (int ni = 0; ni < 4; ++ni)
#pragma unroll
      for (int rr = 0; rr < 4; ++rr) {
        int row = row0 + mi * 16 + g * 4 + rr;
        int col = col0 + ni * 16 + r;
        int h = col >> 6, dd = col & 63;
        size_t bh_ = (size_t)(row >> 10) * 16 + h;
        float v = acc[mi][ni][rr];
        if (matk == 0) {
          v *= aux[col] * 0.125f;  // mixing[h,dd] flat == col; fold 1/sqrt(64)
          o0[(bh_ * 1024 + (row & 1023)) * 64 + dd] = (bf16_t)v;
        } else if (matk == 1) {
          o1[(bh_ * 1024 + (row & 1023)) * 64 + dd] = (bf16_t)v;
        } else {
          o2[(bh_ * 64 + dd) * 1024 + (row & 1023)] = (bf16_t)v;
        }
      }
}

// ---------------- 64x128-tile dense GEMM, K=1024: out = A@Wd^T + bd (fp32, NT) ----------------
__global__ __launch_bounds__(256) void k_gemm_dense(const bf16_t* __restrict__ A,
                                                    const bf16_t* __restrict__ BT,
                                                    const float* __restrict__ bd,
                                                    float* __restrict__ of) {
  constexpr int K = 1024;
  const int tid = threadIdx.x;
  const int w = tid >> 6, lane = tid & 63;
  const int r = lane & 15, g = lane >> 4;
  const int swz = (blockIdx.x & 7) * 64 + (blockIdx.x >> 3);  // XCD-contiguous
  const int nb = swz & 7;
  const int mb = swz >> 3;

  __shared__ bf16_t As[64 * 32];
  __shared__ bf16_t Bs[128 * 32];

  f32x4 acc[2][4] = {};

  const bf16_t* Ag = A + (size_t)(mb * 64 + w * 16 + (lane >> 2)) * K + (lane & 3) * 8;
  const bf16_t* Bg = BT + (size_t)(nb * 128 + w * 32 + (lane >> 2)) * K + (lane & 3) * 8;
  bf16_t* Asw = As + (w * 16) * 32;
  bf16_t* Bsw = Bs + (w * 32) * 32;

  const int wr = w >> 1, wc = w & 1;  // wave -> 32x64 sub-tile
  const int mrow0 = wr * 32, ncol0 = wc * 64;

  for (int k0 = 0; k0 < K; k0 += 32) {
    gload16(Ag + k0, Asw);
    gload16(Bg + k0, Bsw);
    gload16(Bg + 16 * K + k0, Bsw + 16 * 32);
    asm volatile("s_waitcnt vmcnt(0)" ::: "memory");
    __syncthreads();

    bf16x8 av[2], bv[4];
#pragma unroll
    for (int mi = 0; mi < 2; ++mi)
      av[mi] = *reinterpret_cast<const bf16x8*>(As + (mrow0 + mi * 16 + r) * 32 + g * 8);
#pragma unroll
    for (int ni = 0; ni < 4; ++ni)
      bv[ni] = *reinterpret_cast<const bf16x8*>(Bs + (ncol0 + ni * 16 + r) * 32 + g * 8);
#pragma unroll
    for (int mi = 0; mi < 2; ++mi)
#pragma unroll
      for (int ni = 0; ni < 4; ++ni)
        acc[mi][ni] = __builtin_amdgcn_mfma_f32_16x16x32_bf16(av[mi], bv[ni], acc[mi][ni], 0, 0, 0);
    __syncthreads();
  }

  const int row0 = mb * 64 + mrow0, col0 = nb * 128 + ncol0;
#pragma unroll
  for (int mi = 0; mi < 2; ++mi)
#pragma unroll
    for (int ni = 0; ni < 4; ++ni)
#pragma unroll
      for (int rr = 0; rr < 4; ++rr) {
        int row = row0 + mi * 16 + g * 4 + rr;
        int col = col0 + ni * 16 + r;
        __builtin_nontemporal_store(acc[mi][ni][rr] + bd[col], of + (size_t)row * 1024 + col);
      }
}

// ---------------- fused attn v3: LDS-staged K and V (coalesced gload_lds + XOR swizzle) ----------------
// block: one (b,h), 16 q rows; 4 waves. QK^T processes 8 chunks of 128 keys through a
// 16 KB LDS buffer; PV reuses the same buffer for V chunks. All K/V global reads are
// 8-line coalesced wave-instructions (vs 16-line scatter before): attacks the unmeasured
// TA/L1 line-throughput wall (R2-R6: 165us invariant with all counted pipes <15%).
// Swizzle discipline (T2/m173): LDS dest linear, SOURCE pre-permuted col16^=(row&7|15),
// reads apply the same XOR -> conflict-free ds_read_b128.
__global__ __launch_bounds__(256) void k_attn_fused(const bf16_t* __restrict__ Qm,
                                                    const bf16_t* __restrict__ Kw,
                                                    const bf16_t* __restrict__ VT,
                                                    const float* __restrict__ cbm,
                                                    float* __restrict__ P,
                                                    bf16_t* __restrict__ aout) {
  const int tid = threadIdx.x;
  const int w = tid >> 6, lane = tid & 63;
  const int r = lane & 15, g = lane >> 4;
  const int swz = (blockIdx.x & 7) * 512 + (blockIdx.x >> 3);  // XCD-contiguous (b,h) groups
  const int qt = swz & 63;
  const int bh = swz >> 6;
  const int b = bh >> 4, h = bh & 15;
  const int q0 = qt * 16;

  constexpr int PSTR = 1032;  // row stride 2064B = 516 dwords (516%32=4 -> 2-way, free)
  __shared__ bf16_t KVb[128 * 64];     // 16 KB: K chunks [128key][64d], then V chunks [64d][128key]
  __shared__ bf16_t Plds[16 * PSTR];   // 32.25 KB
  __shared__ float red[2][16][4];

  // Q frags (B-operand): lane reads Q[q0 + r][g*8 ..] (+32)
  const bf16_t* qb = Qm + ((size_t)bh * 1024 + q0) * 64;
  bf16x8 bq0 = *reinterpret_cast<const bf16x8*>(qb + r * 64 + g * 8);
  bf16x8 bq1 = *reinterpret_cast<const bf16x8*>(qb + r * 64 + 32 + g * 8);

  // ---- phase 1: QK^T over 8 chunks of 128 keys, K staged in LDS ----
  // K LDS layout [128][64] bf16 (128B rows), col16 swizz: LDS[row][j16] = K[row][j16^(row&7)]
  f32x4 acc[8][2];
  const int sa0 = (g ^ (r & 7)) * 8;        // a0: global col16 g
  const int sa1 = ((4 + g) ^ (r & 7)) * 8;  // a1: global col16 4+g
  for (int c = 0; c < 8; ++c) {
    const bf16_t* kc = Kw + ((size_t)bh * 1024 + c * 128) * 64;
#pragma unroll
    for (int i = 0; i < 4; ++i) {
      const int rowl = i * 32 + (tid >> 3);
      const int c16 = (tid & 7) ^ (rowl & 7);
      gload16(kc + rowl * 64 + c16 * 8, KVb + (i * 32 + w * 8) * 64);
    }
    asm volatile("s_waitcnt vmcnt(0)" ::: "memory");
    __syncthreads();
#pragma unroll
    for (int tt = 0; tt < 2; ++tt) {
      const int krow = (w * 32 + tt * 16 + r) * 64;
      bf16x8 a0 = *reinterpret_cast<const bf16x8*>(KVb + krow + sa0);
      bf16x8 a1 = *reinterpret_cast<const bf16x8*>(KVb + krow + sa1);
      f32x4 cc = {0.f, 0.f, 0.f, 0.f};
      cc = __builtin_amdgcn_mfma_f32_16x16x32_bf16(a0, bq0, cc, 0, 0, 0);
      cc = __builtin_amdgcn_mfma_f32_16x16x32_bf16(a1, bq1, cc, 0, 0, 0);
      acc[c][tt] = cc;
    }
    __syncthreads();
  }

  // ---- softmax: keys per lane = c*128 + w*32 + tt*16 + g*4 + rr, q = r ----
  const float* cv = cbm + (size_t)bh * 1024 + w * 32;
  float mx = -1e30f;
#pragma unroll
  for (int c = 0; c < 8; ++c)
#pragma unroll
    for (int tt = 0; tt < 2; ++tt) {
      f32x4 cl = *reinterpret_cast<const f32x4*>(cv + c * 128 + tt * 16 + g * 4);
      acc[c][tt] += cl;
#pragma unroll
      for (int rr = 0; rr < 4; ++rr) mx = fmaxf(mx, acc[c][tt][rr]);
    }
  mx = fmaxf(mx, __shfl_xor(mx, 16));
  mx = fmaxf(mx, __shfl_xor(mx, 32));
  if (lane < 16) red[0][r][w] = mx;
  __syncthreads();
  const float m = fmaxf(fmaxf(red[0][r][0], red[0][r][1]), fmaxf(red[0][r][2], red[0][r][3]));
  float sum = 0.f;
#pragma unroll
  for (int c = 0; c < 8; ++c)
#pragma unroll
    for (int tt = 0; tt < 2; ++tt)
#pragma unroll
      for (int rr = 0; rr < 4; ++rr) {
        float p = __expf(acc[c][tt][rr] - m);
        acc[c][tt][rr] = p;
        sum += p;
      }
  sum += __shfl_xor(sum, 16);
  sum += __shfl_xor(sum, 32);
  if (lane < 16) red[1][r][w] = sum;
  __syncthreads();
  const float l = 1.f / (red[1][r][0] + red[1][r][1] + red[1][r][2] + red[1][r][3]);

  // normalized P -> LDS (bf16, rows = q)
  bf16_t* pl = Plds + r * PSTR + w * 32;
#pragma unroll
  for (int c = 0; c < 8; ++c)
#pragma unroll
    for (int tt = 0; tt < 2; ++tt) {
      f32x4 pv = acc[c][tt] * l;
      bf16x4 pk = { (bf16_t)pv[0], (bf16_t)pv[1], (bf16_t)pv[2], (bf16_t)pv[3] };
      *reinterpret_cast<bf16x4*>(pl + c * 128 + tt * 16 + g * 4) = pk;
    }

  // ---- phase 2: PV over 8 chunks, V staged into KVb as [64 d][128 key] ----
  // V LDS col16 swizz: LDS[d][j16] = VT[d][chunk + (j16^(d&15))*8 ..]
  // wave w owns d-cols [w*16, +16); A-frag from Plds rows (q=r), B-frag from KVb.
  f32x4 oa0 = {0.f, 0.f, 0.f, 0.f}, oa1 = {0.f, 0.f, 0.f, 0.f};
  const bf16_t* vbase = VT + (size_t)bh * 64 * 1024;
  const int vrow = (w * 16 + r) * 128;
  for (int c = 0; c < 8; ++c) {
    __syncthreads();  // protect KVb (QK readers / prev PV chunk) and publish Plds (c==0)
#pragma unroll
    for (int i = 0; i < 4; ++i) {
      const int row = i * 16 + (tid >> 4);
      const int c16 = (tid & 15) ^ (row & 15);
      gload16(vbase + (size_t)row * 1024 + c * 128 + c16 * 8, KVb + (i * 16 + w * 4) * 128);
    }
    asm volatile("s_waitcnt vmcnt(0)" ::: "memory");
    __syncthreads();
#pragma unroll
    for (int ks = 0; ks < 4; ++ks) {
      bf16x8 av = *reinterpret_cast<const bf16x8*>(Plds + r * PSTR + c * 128 + ks * 32 + g * 8);
      bf16x8 bv = *reinterpret_cast<const bf16x8*>(KVb + vrow + (((ks * 4 + g) ^ r) * 8));
      if (ks & 1) oa1 = __builtin_amdgcn_mfma_f32_16x16x32_bf16(av, bv, oa1, 0, 0, 0);
      else        oa0 = __builtin_amdgcn_mfma_f32_16x16x32_bf16(av, bv, oa0, 0, 0, 0);
    }
  }
  f32x4 oacc = oa0 + oa1;
#pragma unroll
  for (int rr = 0; rr < 4; ++rr)
    aout[((size_t)b * 1024 + q0 + g * 4 + rr) * 1024 + h * 64 + w * 16 + r] = (bf16_t)oacc[rr];

  // ---- phase 3 (LAST): P fp32 coalesced NT store from Plds; drains at wave end ----
  {
    float* pg = P + ((size_t)bh * 1024 + q0) * 1024;
#pragma unroll
    for (int j = 0; j < 4; ++j) {
      const int row = w * 4 + j;
#pragma unroll
      for (int half = 0; half < 2; ++half) {
        const int col = half * 512 + lane * 8;
        bf16x8 v = *reinterpret_cast<const bf16x8*>(Plds + row * PSTR + col);
        f32x4 lo = { (float)v[0], (float)v[1], (float)v[2], (float)v[3] };
        f32x4 hi = { (float)v[4], (float)v[5], (float)v[6], (float)v[7] };
        float* dst = pg + (size_t)row * 1024 + col;
        __builtin_nontemporal_store(lo, reinterpret_cast<f32x4*>(dst));
        __builtin_nontemporal_store(hi, reinterpret_cast<f32x4*>(dst + 4));
      }
    }
  }
}

extern "C" void kernel_launch(void* const* d_in, const int* in_sizes, int n_in,
                              void* d_out, int out_size, void* d_ws, size_t ws_size,
                              hipStream_t stream) {
  const float* x      = (const float*)d_in[0];
  const float* mask   = (const float*)d_in[1];
  const float* Wq     = (const float*)d_in[2];
  const float* Wk     = (const float*)d_in[3];
  const float* Wv     = (const float*)d_in[4];
  const float* Wb     = (const float*)d_in[5];
  const float* mixing = (const float*)d_in[6];
  const float* Wd     = (const float*)d_in[7];
  const float* bd     = (const float*)d_in[8];

  char* ws = (char*)d_ws;
  bf16_t* xb   = (bf16_t*)(ws + 0);         //  8,388,608
  bf16_t* WqT  = (bf16_t*)(ws + 8388608);   //  2,097,152  } contiguous: one
  bf16_t* WkT  = (bf16_t*)(ws + 10485760);  //  2,097,152  } N=3072 B^T for
  bf16_t* WvT  = (bf16_t*)(ws + 12582912);  //  2,097,152  } fused QKV GEMM
  bf16_t* WdT  = (bf16_t*)(ws + 14680064);  //  2,097,152
  bf16_t* Qm   = (bf16_t*)(ws + 16777216);  //  8,388,608  [b,h,s,d] * mixing/8
  bf16_t* Kw   = (bf16_t*)(ws + 25165824);  //  8,388,608  [b,h,s,d]
  bf16_t* VT   = (bf16_t*)(ws + 33554432);  //  8,388,608  [b,h,d,s]
  bf16_t* aout = (bf16_t*)(ws + 41943040);  //  8,388,608  [b,s,(h,hd)]
  float*  cbm  = (float*)(ws + 50331648);   //    262,144  [b,h,s] bias+mask
  if (ws_size < 50593792) return;

  float* outO = (float*)d_out;        // attn_output [4,1024,1024]
  float* outP = outO + 4194304;       // attn_weights [4,16,1024,1024]

  k_cvt_bf16<<<4096, 256, 0, stream>>>(x, xb);
  k_transpose_cvt4<<<dim3(1024, 4), 256, 0, stream>>>(Wq, Wk, Wv, Wd, WqT, WkT, WvT, WdT);
  k_cbias<<<4096, 256, 0, stream>>>(x, Wb, mask, cbm);
  k_gemm_qkv<<<768, 256, 0, stream>>>(xb, WqT, mixing, Qm, Kw, VT);
  k_attn_fused<<<4096, 256, 0, stream>>>(Qm, Kw, VT, cbm, outP, aout);
  k_gemm_dense<<<512, 256, 0, stream>>>(aout, WdT, bd, outO);
}